// Round 2
// baseline (419.359 us; speedup 1.0000x reference)
//
#include <hip/hip_runtime.h>
#include <hip/hip_bf16.h>
#include <stdint.h>

#define B_   32
#define C_   512
#define HW_  3136
#define HID_ 128
#define PT   64     // pixels per block tile
#define XP   72     // xlds pitch (bf16 elems), 16B-aligned b128 frags
#define HP   136    // hlds pitch
#define EPS_ 1e-5f

using frag8  = __attribute__((ext_vector_type(8))) short;  // 8 bf16 (4 VGPRs)
using short8 = __attribute__((ext_vector_type(8))) short;
using f32x4  = __attribute__((ext_vector_type(4))) float;

__device__ __forceinline__ short f2bf(float f) {
    union { float f; uint32_t u; } v; v.f = f;
    uint32_t u = v.u;
    u += 0x7fffu + ((u >> 16) & 1u);   // RNE
    return (short)(u >> 16);
}

// ---------------------------------------------------------------------------
// Prep: fp32 weights -> bf16 panels; panel(mt,kt) is 16x32 bf16, element
// (i, 8q+j) at offset ((q*16+i)*8 + j) so one frag load = lane*8, fully
// coalesced 1KB/wave. Also folds BN into scale/shift.
// ---------------------------------------------------------------------------
__global__ __launch_bounds__(256) void prep_kernel(
    const float* __restrict__ w1_rgb, const float* __restrict__ w2_rgb,
    const float* __restrict__ w1_inf, const float* __restrict__ w2_inf,
    const float* __restrict__ rm_rgb, const float* __restrict__ rv_rgb,
    const float* __restrict__ g_rgb,  const float* __restrict__ b_rgb,
    const float* __restrict__ rm_inf, const float* __restrict__ rv_inf,
    const float* __restrict__ g_inf,  const float* __restrict__ b_inf,
    short* __restrict__ w1p_rgb, short* __restrict__ w1p_inf,
    short* __restrict__ w2p_rgb, short* __restrict__ w2p_inf,
    float* __restrict__ ss)
{
    int t = blockIdx.x * 256 + threadIdx.x;   // 0 .. 65535
    int p = t >> 9, w = t & 511;
    int q = w >> 7, r = (w >> 3) & 15, j = w & 7;
    {   // w1: M=128, K=512 -> 8 x 16 panels
        int mt = p >> 4, kt = p & 15;
        int m = mt * 16 + r, k = kt * 32 + q * 8 + j;
        w1p_rgb[t] = f2bf(w1_rgb[m * C_ + k]);
        w1p_inf[t] = f2bf(w1_inf[m * C_ + k]);
    }
    {   // w2: M=512, K=128 -> 32 x 4 panels
        int mt = p >> 2, kt = p & 3;
        int m = mt * 16 + r, k = kt * 32 + q * 8 + j;
        w2p_rgb[t] = f2bf(w2_rgb[m * HID_ + k]);
        w2p_inf[t] = f2bf(w2_inf[m * HID_ + k]);
    }
    if (t < 128) {
        float sc = g_rgb[t] * rsqrtf(rv_rgb[t] + EPS_);
        ss[t] = sc; ss[128 + t] = b_rgb[t] - rm_rgb[t] * sc;
    } else if (t < 256) {
        int i = t - 128;
        float sc = g_inf[i] * rsqrtf(rv_inf[i] + EPS_);
        ss[256 + i] = sc; ss[384 + i] = b_inf[i] - rm_inf[i] * sc;
    }
}

// ---------------------------------------------------------------------------
// Fused, software-pipelined:
//   stage1: h(128x64) = w1_sel @ x-tile (K=512), dbuf LDS, 1 barrier/chunk
//   stage2: out^layout (pixel-major frags) -> dwordx4 nontemporal stores
// ---------------------------------------------------------------------------
__global__ __launch_bounds__(256) void fused_kernel(
    const float* __restrict__ x, const int* __restrict__ mod,
    const short* __restrict__ w1p_rgb, const short* __restrict__ w1p_inf,
    const short* __restrict__ w2p_rgb, const short* __restrict__ w2p_inf,
    const float* __restrict__ ss, float* __restrict__ out)
{
    __shared__ short xlds[2][PT * XP];  // double-buffered x chunk (64ch x 64px)
    __shared__ short hlds[PT * HP];     // h (pixel-major, 128 hid)

    const int tid  = threadIdx.x;
    const int lane = tid & 63;
    const int wave = tid >> 6;
    const int i16  = lane & 15;
    const int q    = lane >> 4;
    const int b    = blockIdx.y;
    const int p0   = blockIdx.x * PT;

    const int is_rgb = (mod[b] == 1);
    const short* __restrict__ w1p = is_rgb ? w1p_rgb : w1p_inf;
    const short* __restrict__ w2p = is_rgb ? w2p_rgb : w2p_inf;
    const float* __restrict__ scale = ss + (is_rgb ? 0 : 256);
    const float* __restrict__ shift = scale + 128;

    f32x4 acc1[2][4];
    #pragma unroll
    for (int mt = 0; mt < 2; ++mt)
        #pragma unroll
        for (int nt = 0; nt < 4; ++nt)
            acc1[mt][nt] = (f32x4){0.f, 0.f, 0.f, 0.f};

    // staging: thread owns pixel=lane, wave owns 8-channel groups {8w, 8w+32}
    const int px    = lane;
    const int cbase = wave * 8;
    const float* __restrict__ xb = x + (size_t)b * C_ * HW_ + p0 + px;

    float rA[16], rB[16];
    #pragma unroll
    for (int it = 0; it < 2; ++it)
        #pragma unroll
        for (int j = 0; j < 8; ++j)
            rA[it * 8 + j] = xb[(size_t)(cbase + it * 32 + j) * HW_];

    #pragma unroll 1
    for (int k2 = 0; k2 < 4; ++k2) {
        const int kcA = k2 * 2, kcB = kcA + 1;

        // convert rA -> xlds[0]  (b128 writes, conflict-free)
        #pragma unroll
        for (int it = 0; it < 2; ++it) {
            short8 pk;
            #pragma unroll
            for (int j = 0; j < 8; ++j) pk[j] = f2bf(rA[it * 8 + j]);
            *(short8*)(&xlds[0][px * XP + cbase + it * 32]) = pk;
        }
        __syncthreads();

        // issue loads for chunk kcB — overlap the mfma phase below
        #pragma unroll
        for (int it = 0; it < 2; ++it)
            #pragma unroll
            for (int j = 0; j < 8; ++j)
                rB[it * 8 + j] = xb[(size_t)(kcB * 64 + cbase + it * 32 + j) * HW_];

        // mfma on xlds[0] (chunk kcA)
        {
            frag8 af[2][2];
            #pragma unroll
            for (int kk = 0; kk < 2; ++kk) {
                int kt = kcA * 2 + kk;
                #pragma unroll
                for (int mt = 0; mt < 2; ++mt)
                    af[kk][mt] = *(const frag8*)(w1p + (((wave * 2 + mt) * 16 + kt) << 9) + lane * 8);
            }
            #pragma unroll
            for (int kk = 0; kk < 2; ++kk) {
                frag8 bfr[4];
                #pragma unroll
                for (int nt = 0; nt < 4; ++nt)
                    bfr[nt] = *(const frag8*)(&xlds[0][(nt * 16 + i16) * XP + kk * 32 + q * 8]);
                #pragma unroll
                for (int mt = 0; mt < 2; ++mt)
                    #pragma unroll
                    for (int nt = 0; nt < 4; ++nt)
                        acc1[mt][nt] = __builtin_amdgcn_mfma_f32_16x16x32_bf16(
                            af[kk][mt], bfr[nt], acc1[mt][nt], 0, 0, 0);
            }
        }

        // convert rB -> xlds[1]
        #pragma unroll
        for (int it = 0; it < 2; ++it) {
            short8 pk;
            #pragma unroll
            for (int j = 0; j < 8; ++j) pk[j] = f2bf(rB[it * 8 + j]);
            *(short8*)(&xlds[1][px * XP + cbase + it * 32]) = pk;
        }
        __syncthreads();

        // issue loads for next even chunk — overlap mfma on xlds[1]
        if (k2 < 3) {
            #pragma unroll
            for (int it = 0; it < 2; ++it)
                #pragma unroll
                for (int j = 0; j < 8; ++j)
                    rA[it * 8 + j] = xb[(size_t)((kcA + 2) * 64 + cbase + it * 32 + j) * HW_];
        }

        // mfma on xlds[1] (chunk kcB)
        {
            frag8 af[2][2];
            #pragma unroll
            for (int kk = 0; kk < 2; ++kk) {
                int kt = kcB * 2 + kk;
                #pragma unroll
                for (int mt = 0; mt < 2; ++mt)
                    af[kk][mt] = *(const frag8*)(w1p + (((wave * 2 + mt) * 16 + kt) << 9) + lane * 8);
            }
            #pragma unroll
            for (int kk = 0; kk < 2; ++kk) {
                frag8 bfr[4];
                #pragma unroll
                for (int nt = 0; nt < 4; ++nt)
                    bfr[nt] = *(const frag8*)(&xlds[1][(nt * 16 + i16) * XP + kk * 32 + q * 8]);
                #pragma unroll
                for (int mt = 0; mt < 2; ++mt)
                    #pragma unroll
                    for (int nt = 0; nt < 4; ++nt)
                        acc1[mt][nt] = __builtin_amdgcn_mfma_f32_16x16x32_bf16(
                            af[kk][mt], bfr[nt], acc1[mt][nt], 0, 0, 0);
            }
        }
    }

    // ---- BN + ReLU -> hlds (bf16, pixel-major) ----
    #pragma unroll
    for (int mt = 0; mt < 2; ++mt) {
        int mbase = wave * 32 + mt * 16 + q * 4;
        float s0 = scale[mbase + 0], s1 = scale[mbase + 1];
        float s2 = scale[mbase + 2], s3 = scale[mbase + 3];
        float h0 = shift[mbase + 0], h1 = shift[mbase + 1];
        float h2 = shift[mbase + 2], h3 = shift[mbase + 3];
        #pragma unroll
        for (int nt = 0; nt < 4; ++nt) {
            int p = nt * 16 + i16;
            short4 pk = make_short4(
                f2bf(fmaxf(acc1[mt][nt][0] * s0 + h0, 0.f)),
                f2bf(fmaxf(acc1[mt][nt][1] * s1 + h1, 0.f)),
                f2bf(fmaxf(acc1[mt][nt][2] * s2 + h2, 0.f)),
                f2bf(fmaxf(acc1[mt][nt][3] * s3 + h3, 0.f)));
            *(short4*)(&hlds[p * HP + mbase]) = pk;
        }
    }
    __syncthreads();

    // ---- Stage 2 (transposed): D[pixel][channel]; lane's 4 regs = 4
    // consecutive pixels -> dwordx4 nontemporal stores ----
    #pragma unroll 1
    for (int half = 0; half < 2; ++half) {
        f32x4 acc2[4][4];   // [pixel-tile][channel-tile]
        #pragma unroll
        for (int pt = 0; pt < 4; ++pt)
            #pragma unroll
            for (int ct = 0; ct < 4; ++ct)
                acc2[pt][ct] = (f32x4){0.f, 0.f, 0.f, 0.f};

        #pragma unroll
        for (int kt = 0; kt < 4; ++kt) {
            frag8 wf[4];   // B operand: w2[n=channel][k=hid]
            #pragma unroll
            for (int ct = 0; ct < 4; ++ct) {
                int ctg = half * 16 + wave * 4 + ct;
                wf[ct] = *(const frag8*)(w2p + ((ctg * 4 + kt) << 9) + lane * 8);
            }
            frag8 hf[4];   // A operand: h[m=pixel][k=hid]
            #pragma unroll
            for (int pt = 0; pt < 4; ++pt)
                hf[pt] = *(const frag8*)(&hlds[(pt * 16 + i16) * HP + kt * 32 + q * 8]);
            #pragma unroll
            for (int pt = 0; pt < 4; ++pt)
                #pragma unroll
                for (int ct = 0; ct < 4; ++ct)
                    acc2[pt][ct] = __builtin_amdgcn_mfma_f32_16x16x32_bf16(
                        hf[pt], wf[ct], acc2[pt][ct], 0, 0, 0);
        }
        #pragma unroll
        for (int ct = 0; ct < 4; ++ct) {
            int crow = (half * 16 + wave * 4 + ct) * 16 + i16;
            float* obase = out + ((size_t)(b * C_ + crow)) * HW_ + p0 + q * 4;
            #pragma unroll
            for (int pt = 0; pt < 4; ++pt)
                __builtin_nontemporal_store(acc2[pt][ct], (f32x4*)(obase + pt * 16));
        }
    }
}

extern "C" void kernel_launch(void* const* d_in, const int* in_sizes, int n_in,
                              void* d_out, int out_size, void* d_ws, size_t ws_size,
                              hipStream_t stream) {
    const float* x      = (const float*)d_in[0];
    const int*   mod    = (const int*)d_in[1];
    const float* w1_rgb = (const float*)d_in[2];
    const float* rm_rgb = (const float*)d_in[3];
    const float* rv_rgb = (const float*)d_in[4];
    const float* g_rgb  = (const float*)d_in[5];
    const float* b_rgb  = (const float*)d_in[6];
    const float* w2_rgb = (const float*)d_in[7];
    const float* w1_inf = (const float*)d_in[8];
    const float* rm_inf = (const float*)d_in[9];
    const float* rv_inf = (const float*)d_in[10];
    const float* g_inf  = (const float*)d_in[11];
    const float* b_inf  = (const float*)d_in[12];
    const float* w2_inf = (const float*)d_in[13];
    float* out = (float*)d_out;

    char* ws = (char*)d_ws;
    short* w1p_rgb = (short*)(ws + 0);
    short* w1p_inf = (short*)(ws + 131072);
    short* w2p_rgb = (short*)(ws + 262144);
    short* w2p_inf = (short*)(ws + 393216);
    float* ss      = (float*)(ws + 524288);   // 512 floats

    prep_kernel<<<256, 256, 0, stream>>>(
        w1_rgb, w2_rgb, w1_inf, w2_inf,
        rm_rgb, rv_rgb, g_rgb, b_rgb,
        rm_inf, rv_inf, g_inf, b_inf,
        w1p_rgb, w1p_inf, w2p_rgb, w2p_inf, ss);

    dim3 grid(HW_ / PT, B_);
    fused_kernel<<<grid, 256, 0, stream>>>(
        x, mod, w1p_rgb, w1p_inf, w2p_rgb, w2p_inf, ss, out);
}

// Round 3
// 394.672 us; speedup vs baseline: 1.0626x; 1.0626x over previous
//
#include <hip/hip_runtime.h>
#include <hip/hip_bf16.h>
#include <stdint.h>

#define B_   32
#define C_   512
#define HW_  3136
#define HID_ 128
#define PT   64     // pixels per block tile
#define XP   72     // xlds pitch (bf16 elems), 16B-aligned b128 frags
#define HP   136    // hlds pitch
#define EPS_ 1e-5f

using frag8  = __attribute__((ext_vector_type(8))) short;  // 8 bf16 (4 VGPRs)
using short8 = __attribute__((ext_vector_type(8))) short;
using f32x4  = __attribute__((ext_vector_type(4))) float;

__device__ __forceinline__ short f2bf(float f) {
    union { float f; uint32_t u; } v; v.f = f;
    uint32_t u = v.u;
    u += 0x7fffu + ((u >> 16) & 1u);   // RNE
    return (short)(u >> 16);
}

// ---------------------------------------------------------------------------
// Prep: fp32 weights -> bf16 panels; panel(mt,kt) is 16x32 bf16, element
// (i, 8q+j) at offset ((q*16+i)*8 + j) so one frag load = lane*8, fully
// coalesced 1KB/wave. Also folds BN into scale/shift.
// ---------------------------------------------------------------------------
__global__ __launch_bounds__(256) void prep_kernel(
    const float* __restrict__ w1_rgb, const float* __restrict__ w2_rgb,
    const float* __restrict__ w1_inf, const float* __restrict__ w2_inf,
    const float* __restrict__ rm_rgb, const float* __restrict__ rv_rgb,
    const float* __restrict__ g_rgb,  const float* __restrict__ b_rgb,
    const float* __restrict__ rm_inf, const float* __restrict__ rv_inf,
    const float* __restrict__ g_inf,  const float* __restrict__ b_inf,
    short* __restrict__ w1p_rgb, short* __restrict__ w1p_inf,
    short* __restrict__ w2p_rgb, short* __restrict__ w2p_inf,
    float* __restrict__ ss)
{
    int t = blockIdx.x * 256 + threadIdx.x;   // 0 .. 65535
    int p = t >> 9, w = t & 511;
    int q = w >> 7, r = (w >> 3) & 15, j = w & 7;
    {   // w1: M=128, K=512 -> 8 x 16 panels
        int mt = p >> 4, kt = p & 15;
        int m = mt * 16 + r, k = kt * 32 + q * 8 + j;
        w1p_rgb[t] = f2bf(w1_rgb[m * C_ + k]);
        w1p_inf[t] = f2bf(w1_inf[m * C_ + k]);
    }
    {   // w2: M=512, K=128 -> 32 x 4 panels
        int mt = p >> 2, kt = p & 3;
        int m = mt * 16 + r, k = kt * 32 + q * 8 + j;
        w2p_rgb[t] = f2bf(w2_rgb[m * HID_ + k]);
        w2p_inf[t] = f2bf(w2_inf[m * HID_ + k]);
    }
    if (t < 128) {
        float sc = g_rgb[t] * rsqrtf(rv_rgb[t] + EPS_);
        ss[t] = sc; ss[128 + t] = b_rgb[t] - rm_rgb[t] * sc;
    } else if (t < 256) {
        int i = t - 128;
        float sc = g_inf[i] * rsqrtf(rv_inf[i] + EPS_);
        ss[256 + i] = sc; ss[384 + i] = b_inf[i] - rm_inf[i] * sc;
    }
}

// ---------------------------------------------------------------------------
// Fused, depth-2 software-pipelined stage 1 (3-buffer register belt, dbuf
// LDS, 1 barrier/chunk); transposed stage 2 with plain dwordx4 stores.
// ---------------------------------------------------------------------------
__global__ __launch_bounds__(256) void fused_kernel(
    const float* __restrict__ x, const int* __restrict__ mod,
    const short* __restrict__ w1p_rgb, const short* __restrict__ w1p_inf,
    const short* __restrict__ w2p_rgb, const short* __restrict__ w2p_inf,
    const float* __restrict__ ss, float* __restrict__ out)
{
    __shared__ short xlds[2][PT * XP];  // double-buffered x chunk (64ch x 64px)
    __shared__ short hlds[PT * HP];     // h (pixel-major, 128 hid)

    const int tid  = threadIdx.x;
    const int lane = tid & 63;
    const int wave = tid >> 6;
    const int i16  = lane & 15;
    const int q    = lane >> 4;
    const int b    = blockIdx.y;
    const int p0   = blockIdx.x * PT;

    const int is_rgb = (mod[b] == 1);
    const short* __restrict__ w1p = is_rgb ? w1p_rgb : w1p_inf;
    const short* __restrict__ w2p = is_rgb ? w2p_rgb : w2p_inf;
    const float* __restrict__ scale = ss + (is_rgb ? 0 : 256);
    const float* __restrict__ shift = scale + 128;

    f32x4 acc1[2][4];
    #pragma unroll
    for (int mt = 0; mt < 2; ++mt)
        #pragma unroll
        for (int nt = 0; nt < 4; ++nt)
            acc1[mt][nt] = (f32x4){0.f, 0.f, 0.f, 0.f};

    // staging: thread owns pixel=lane, wave owns 8-channel groups {8w, 8w+32}
    const int px    = lane;
    const int cbase = wave * 8;
    const float* __restrict__ xb = x + (size_t)b * C_ * HW_ + p0 + px;

    // 3-deep register belt: chunk c lives in r[c % 3]
    float r[3][16];
    #pragma unroll
    for (int c0 = 0; c0 < 2; ++c0)
        #pragma unroll
        for (int it = 0; it < 2; ++it)
            #pragma unroll
            for (int j = 0; j < 8; ++j)
                r[c0][it * 8 + j] =
                    xb[(size_t)(c0 * 64 + cbase + it * 32 + j) * HW_];

    #pragma unroll
    for (int c = 0; c < 8; ++c) {
        const int rb = c % 3, lb = c & 1;

        // convert chunk c -> xlds[lb]  (b128 writes, conflict-free)
        #pragma unroll
        for (int it = 0; it < 2; ++it) {
            short8 pk;
            #pragma unroll
            for (int j = 0; j < 8; ++j) pk[j] = f2bf(r[rb][it * 8 + j]);
            *(short8*)(&xlds[lb][px * XP + cbase + it * 32]) = pk;
        }
        __syncthreads();

        // issue loads for chunk c+2 (distance-2 prefetch, overlaps 2 mfma
        // phases + convert before the data is needed)
        if (c + 2 < 8) {
            #pragma unroll
            for (int it = 0; it < 2; ++it)
                #pragma unroll
                for (int j = 0; j < 8; ++j)
                    r[(c + 2) % 3][it * 8 + j] =
                        xb[(size_t)((c + 2) * 64 + cbase + it * 32 + j) * HW_];
        }

        // mfma on xlds[lb] (chunk c: kt = 2c, 2c+1)
        frag8 af[2][2];
        #pragma unroll
        for (int kk = 0; kk < 2; ++kk) {
            int kt = c * 2 + kk;
            #pragma unroll
            for (int mt = 0; mt < 2; ++mt)
                af[kk][mt] = *(const frag8*)(w1p + (((wave * 2 + mt) * 16 + kt) << 9) + lane * 8);
        }
        #pragma unroll
        for (int kk = 0; kk < 2; ++kk) {
            frag8 bfr[4];
            #pragma unroll
            for (int nt = 0; nt < 4; ++nt)
                bfr[nt] = *(const frag8*)(&xlds[lb][(nt * 16 + i16) * XP + kk * 32 + q * 8]);
            #pragma unroll
            for (int mt = 0; mt < 2; ++mt)
                #pragma unroll
                for (int nt = 0; nt < 4; ++nt)
                    acc1[mt][nt] = __builtin_amdgcn_mfma_f32_16x16x32_bf16(
                        af[kk][mt], bfr[nt], acc1[mt][nt], 0, 0, 0);
        }
    }

    // ---- BN + ReLU -> hlds (bf16, pixel-major) ----
    #pragma unroll
    for (int mt = 0; mt < 2; ++mt) {
        int mbase = wave * 32 + mt * 16 + q * 4;
        float s0 = scale[mbase + 0], s1 = scale[mbase + 1];
        float s2 = scale[mbase + 2], s3 = scale[mbase + 3];
        float h0 = shift[mbase + 0], h1 = shift[mbase + 1];
        float h2 = shift[mbase + 2], h3 = shift[mbase + 3];
        #pragma unroll
        for (int nt = 0; nt < 4; ++nt) {
            int p = nt * 16 + i16;
            short4 pk = make_short4(
                f2bf(fmaxf(acc1[mt][nt][0] * s0 + h0, 0.f)),
                f2bf(fmaxf(acc1[mt][nt][1] * s1 + h1, 0.f)),
                f2bf(fmaxf(acc1[mt][nt][2] * s2 + h2, 0.f)),
                f2bf(fmaxf(acc1[mt][nt][3] * s3 + h3, 0.f)));
            *(short4*)(&hlds[p * HP + mbase]) = pk;
        }
    }
    __syncthreads();

    // ---- Stage 2 (transposed): D[pixel][channel]; lane's 4 acc regs = 4
    // consecutive pixels -> plain dwordx4 stores (L2 combines 64B segments;
    // nontemporal here cost +60MB WRITE_SIZE in round 2 — keep plain!) ----
    #pragma unroll 1
    for (int half = 0; half < 2; ++half) {
        f32x4 acc2[4][4];   // [pixel-tile][channel-tile]
        #pragma unroll
        for (int pt = 0; pt < 4; ++pt)
            #pragma unroll
            for (int ct = 0; ct < 4; ++ct)
                acc2[pt][ct] = (f32x4){0.f, 0.f, 0.f, 0.f};

        #pragma unroll
        for (int kt = 0; kt < 4; ++kt) {
            frag8 wf[4];   // B operand: w2[n=channel][k=hid]
            #pragma unroll
            for (int ct = 0; ct < 4; ++ct) {
                int ctg = half * 16 + wave * 4 + ct;
                wf[ct] = *(const frag8*)(w2p + ((ctg * 4 + kt) << 9) + lane * 8);
            }
            frag8 hf[4];   // A operand: h[m=pixel][k=hid]
            #pragma unroll
            for (int pt = 0; pt < 4; ++pt)
                hf[pt] = *(const frag8*)(&hlds[(pt * 16 + i16) * HP + kt * 32 + q * 8]);
            #pragma unroll
            for (int pt = 0; pt < 4; ++pt)
                #pragma unroll
                for (int ct = 0; ct < 4; ++ct)
                    acc2[pt][ct] = __builtin_amdgcn_mfma_f32_16x16x32_bf16(
                        hf[pt], wf[ct], acc2[pt][ct], 0, 0, 0);
        }
        #pragma unroll
        for (int ct = 0; ct < 4; ++ct) {
            int crow = (half * 16 + wave * 4 + ct) * 16 + i16;
            float* obase = out + ((size_t)(b * C_ + crow)) * HW_ + p0 + q * 4;
            #pragma unroll
            for (int pt = 0; pt < 4; ++pt)
                *(f32x4*)(obase + pt * 16) = acc2[pt][ct];
        }
    }
}

extern "C" void kernel_launch(void* const* d_in, const int* in_sizes, int n_in,
                              void* d_out, int out_size, void* d_ws, size_t ws_size,
                              hipStream_t stream) {
    const float* x      = (const float*)d_in[0];
    const int*   mod    = (const int*)d_in[1];
    const float* w1_rgb = (const float*)d_in[2];
    const float* rm_rgb = (const float*)d_in[3];
    const float* rv_rgb = (const float*)d_in[4];
    const float* g_rgb  = (const float*)d_in[5];
    const float* b_rgb  = (const float*)d_in[6];
    const float* w2_rgb = (const float*)d_in[7];
    const float* w1_inf = (const float*)d_in[8];
    const float* rm_inf = (const float*)d_in[9];
    const float* rv_inf = (const float*)d_in[10];
    const float* g_inf  = (const float*)d_in[11];
    const float* b_inf  = (const float*)d_in[12];
    const float* w2_inf = (const float*)d_in[13];
    float* out = (float*)d_out;

    char* ws = (char*)d_ws;
    short* w1p_rgb = (short*)(ws + 0);
    short* w1p_inf = (short*)(ws + 131072);
    short* w2p_rgb = (short*)(ws + 262144);
    short* w2p_inf = (short*)(ws + 393216);
    float* ss      = (float*)(ws + 524288);   // 512 floats

    prep_kernel<<<256, 256, 0, stream>>>(
        w1_rgb, w2_rgb, w1_inf, w2_inf,
        rm_rgb, rv_rgb, g_rgb, b_rgb,
        rm_inf, rv_inf, g_inf, b_inf,
        w1p_rgb, w1p_inf, w2p_rgb, w2p_inf, ss);

    dim3 grid(HW_ / PT, B_);
    fused_kernel<<<grid, 256, 0, stream>>>(
        x, mod, w1p_rgb, w1p_inf, w2p_rgb, w2p_inf, ss, out);
}